// Round 21
// baseline (277.431 us; speedup 1.0000x reference)
//
#include <hip/hip_runtime.h>
#include <hip/hip_bf16.h>
#include <cstdint>
#include <cstddef>

// Decoder cell: B=2, S=T=2048, D=1024, H=16, HD=64.
// Round 21: R20 (267.8us best) + 2-way split-KV for the non-causal layer-2
// attention (grid 1024 = 2 splits x 16 qt x 32 bh, VSINGLE 48KB body ->
// 3 blocks/CU co-residency) + fp32 partial-combine kernel. Partials reuse
// dead buffers (bS0/bH/Khb/Vhb, all consumed before attn2) -- no ws growth.

#define D_DIM 1024
#define SEQ   2048
#define NHEAD 16
#define HDIM  64
#define MROWS 4096

typedef __attribute__((ext_vector_type(8)))  short bf16x8;
typedef __attribute__((ext_vector_type(4)))  float f32x4;
typedef __attribute__((ext_vector_type(16))) float f32x16;
typedef __attribute__((ext_vector_type(4)))  unsigned int u32x4;

static __device__ __forceinline__ short f2bf(float x) {
    __hip_bfloat16 h = __float2bfloat16(x);
    return *reinterpret_cast<short*>(&h);
}

static __device__ __forceinline__ unsigned int cvtpk(float lo, float hi2) {
    unsigned int r;
    asm("v_cvt_pk_bf16_f32 %0, %1, %2" : "=v"(r) : "v"(lo), "v"(hi2));
    return r;
}

#define GLOAD_LDS16(g, l)                                                     \
    __builtin_amdgcn_global_load_lds(                                         \
        (const __attribute__((address_space(1))) unsigned int*)(g),           \
        (__attribute__((address_space(3))) unsigned int*)(l), 16, 0, 0)

struct WPtrs { const float* p[9]; };
struct OPtrs { float* p[4]; };   // [sp*2 + (bh>>4)] -> 16 heads x 2048 x 64 fp32

// ---------------------------------------------------------------------------
// Fused prep: weight transpose+convert (0..2303), fp32->bf16 S0/H
// (2304..6399), bias concat (6400..6419).
// ---------------------------------------------------------------------------
__global__ __launch_bounds__(256) void prep_kernel(
    WPtrs wp, short* __restrict__ Wt,
    const float* __restrict__ s0, const float* __restrict__ hx,
    short* __restrict__ d0, short* __restrict__ d1,
    const float* __restrict__ bq1, const float* __restrict__ bk1,
    const float* __restrict__ bv1, const float* __restrict__ bk2,
    const float* __restrict__ bv2, float* __restrict__ cb1,
    float* __restrict__ cb2)
{
    __shared__ float tl[64][65];
    const int t = threadIdx.x;
    const int id = blockIdx.x;
    if (id < 2304) {
        const int z = id >> 8, rem = id & 255;
        const float* src = wp.p[z];
        short* dst = Wt + (size_t)z * D_DIM * D_DIM;
        const int r0 = (rem >> 4) * 64;
        const int c0 = (rem & 15) * 64;
        #pragma unroll
        for (int i = 0; i < 4; ++i) {
            int row = i * 16 + (t >> 4);
            int col = (t & 15) * 4;
            float4 v = *(const float4*)(src + (size_t)(r0 + row) * D_DIM + c0 + col);
            tl[row][col + 0] = v.x; tl[row][col + 1] = v.y;
            tl[row][col + 2] = v.z; tl[row][col + 3] = v.w;
        }
        __syncthreads();
        #pragma unroll
        for (int i = 0; i < 4; ++i) {
            int nrow = i * 16 + (t >> 4);
            int kcol = (t & 15) * 4;
            ushort4 o;
            o.x = (unsigned short)f2bf(tl[kcol + 0][nrow]);
            o.y = (unsigned short)f2bf(tl[kcol + 1][nrow]);
            o.z = (unsigned short)f2bf(tl[kcol + 2][nrow]);
            o.w = (unsigned short)f2bf(tl[kcol + 3][nrow]);
            *(ushort4*)(dst + (size_t)(c0 + nrow) * D_DIM + r0 + kcol) = o;
        }
    } else if (id < 6400) {
        const int cid = id - 2304;
        const bool second = cid >= 2048;
        const float* src = second ? hx : s0;
        short* dst = second ? d1 : d0;
        size_t i = ((size_t)(cid - (second ? 2048 : 0)) * 256 + t) * 8;
        float4 a = *(const float4*)(src + i);
        float4 b = *(const float4*)(src + i + 4);
        bf16x8 o;
        o[0] = f2bf(a.x); o[1] = f2bf(a.y); o[2] = f2bf(a.z); o[3] = f2bf(a.w);
        o[4] = f2bf(b.x); o[5] = f2bf(b.y); o[6] = f2bf(b.z); o[7] = f2bf(b.w);
        *(bf16x8*)(dst + i) = o;
    } else {
        const int i = (id - 6400) * 256 + t;
        if      (i < 1024) cb1[i] = bq1[i];
        else if (i < 2048) cb1[i] = bk1[i - 1024];
        else if (i < 3072) cb1[i] = bv1[i - 2048];
        else if (i < 4096) cb2[i - 3072] = bk2[i - 3072];
        else               cb2[i - 3072] = bv2[i - 4096];
    }
}

// ---------------------------------------------------------------------------
// QKV-projection GEMM body: 128x128 tile, BK=32, 4 waves, 16x16x32 MFMA.
// ---------------------------------------------------------------------------
__device__ __forceinline__ void gemm_qkv_body(
    short* __restrict__ As_, short* __restrict__ Bs_,
    const short* __restrict__ A, const short* __restrict__ Bt,
    const float* __restrict__ bias,
    short* __restrict__ Qh, short* __restrict__ Kh, short* __restrict__ Vh,
    int col0, float qscale, int bx, int by)
{
    const int t = threadIdx.x;
    const int wave = t >> 6, lane = t & 63;
    const int wm = wave >> 1, wn = wave & 1;
    const int m0 = bx * 128, n0 = by * 128;
    const int l15 = lane & 15, l4 = lane >> 4;
    const int lrow = lane >> 2, lcol = (lane & 3) * 8;
    f32x4 acc[4][4] = {};
    for (int k0 = 0; k0 < D_DIM; k0 += 32) {
        __syncthreads();
        #pragma unroll
        for (int c = 0; c < 2; ++c) {
            int chunk = wave + c * 4;
            int row = chunk * 16 + lrow;
            GLOAD_LDS16(A  + (size_t)(m0 + row) * D_DIM + k0 + lcol,
                        As_ + chunk * 512 + lane * 8);
            GLOAD_LDS16(Bt + (size_t)(n0 + row) * D_DIM + k0 + lcol,
                        Bs_ + chunk * 512 + lane * 8);
        }
        __syncthreads();
        bf16x8 af[4], bfr[4];
        const int kq = l4 * 8;
        #pragma unroll
        for (int i = 0; i < 4; ++i)
            af[i] = *(const bf16x8*)&As_[(wm * 64 + i * 16 + l15) * 32 + kq];
        #pragma unroll
        for (int j = 0; j < 4; ++j)
            bfr[j] = *(const bf16x8*)&Bs_[(wn * 64 + j * 16 + l15) * 32 + kq];
        #pragma unroll
        for (int i = 0; i < 4; ++i)
            #pragma unroll
            for (int j = 0; j < 4; ++j)
                acc[i][j] = __builtin_amdgcn_mfma_f32_16x16x32_bf16(
                    af[i], bfr[j], acc[i][j], 0, 0, 0);
    }
    const int rbase = m0 + wm * 64;
    const int cbase = n0 + wn * 64;
    float bv[4];
    #pragma unroll
    for (int j = 0; j < 4; ++j) bv[j] = bias[cbase + j * 16 + l15];
    #pragma unroll
    for (int i = 0; i < 4; ++i) {
        #pragma unroll
        for (int r = 0; r < 4; ++r) {
            const int grow = rbase + i * 16 + l4 * 4 + r;
            const int b = grow >> 11, s = grow & 2047;
            #pragma unroll
            for (int j = 0; j < 4; ++j) {
                const int vcol = col0 + cbase + j * 16 + l15;
                float v = acc[i][j][r] + bv[j];
                if (vcol < 1024) v *= qscale;
                short* dst = (vcol < 1024) ? Qh : ((vcol < 2048) ? Kh : Vh);
                const int h = (vcol >> 6) & 15, hd = vcol & 63;
                dst[((size_t)(b * 16 + h) * SEQ + s) * HDIM + hd] = f2bf(v);
            }
        }
    }
}

__global__ __launch_bounds__(256) void gemm_qkv_kernel(
    const short* __restrict__ A, const short* __restrict__ Bt,
    const float* __restrict__ bias,
    short* __restrict__ Qh, short* __restrict__ Kh, short* __restrict__ Vh,
    int col0, float qscale)
{
    __shared__ short lds[8192];
    gemm_qkv_body(lds, lds + 4096, A, Bt, bias, Qh, Kh, Vh,
                  col0, qscale, blockIdx.x, blockIdx.y);
}

// ---------------------------------------------------------------------------
// GEMM variant A: 128x64 tile, fp32 output + residual (out-proj / FFN).
// ---------------------------------------------------------------------------
__global__ __launch_bounds__(256) void gemm_resid_kernel(
    const short* __restrict__ A, const short* __restrict__ Bt,
    const float* __restrict__ bias, const float* __restrict__ resid,
    float* __restrict__ Cout)
{
    __shared__ short As[128 * 32];
    __shared__ short Bs[64 * 32];
    const int t = threadIdx.x;
    const int wave = t >> 6, lane = t & 63;
    const int wm = wave >> 1, wn = wave & 1;
    const int m0 = blockIdx.x * 128, n0 = blockIdx.y * 64;
    const int l15 = lane & 15, l4 = lane >> 4;
    const int lrow = lane >> 2, lcol = (lane & 3) * 8;
    f32x4 acc[4][2] = {};
    for (int k0 = 0; k0 < D_DIM; k0 += 32) {
        __syncthreads();
        #pragma unroll
        for (int c = 0; c < 2; ++c) {
            int chunk = wave + c * 4;
            int row = chunk * 16 + lrow;
            GLOAD_LDS16(A + (size_t)(m0 + row) * D_DIM + k0 + lcol,
                        As + chunk * 512 + lane * 8);
        }
        {
            int row = wave * 16 + lrow;
            GLOAD_LDS16(Bt + (size_t)(n0 + row) * D_DIM + k0 + lcol,
                        Bs + wave * 512 + lane * 8);
        }
        __syncthreads();
        bf16x8 af[4], bfr[2];
        const int kq = l4 * 8;
        #pragma unroll
        for (int i = 0; i < 4; ++i)
            af[i] = *(const bf16x8*)&As[(wm * 64 + i * 16 + l15) * 32 + kq];
        #pragma unroll
        for (int j = 0; j < 2; ++j)
            bfr[j] = *(const bf16x8*)&Bs[(wn * 32 + j * 16 + l15) * 32 + kq];
        #pragma unroll
        for (int i = 0; i < 4; ++i)
            #pragma unroll
            for (int j = 0; j < 2; ++j)
                acc[i][j] = __builtin_amdgcn_mfma_f32_16x16x32_bf16(
                    af[i], bfr[j], acc[i][j], 0, 0, 0);
    }
    const int rbase = m0 + wm * 64;
    const int cbase = n0 + wn * 32;
    float bv[2];
    #pragma unroll
    for (int j = 0; j < 2; ++j) bv[j] = bias[cbase + j * 16 + l15];
    #pragma unroll
    for (int i = 0; i < 4; ++i) {
        #pragma unroll
        for (int r = 0; r < 4; ++r) {
            const int grow = rbase + i * 16 + l4 * 4 + r;
            #pragma unroll
            for (int j = 0; j < 2; ++j) {
                const int gcol = cbase + j * 16 + l15;
                float v = acc[i][j][r] + bv[j]
                        + resid[(size_t)grow * D_DIM + gcol];
                Cout[(size_t)grow * D_DIM + gcol] = v;
            }
        }
    }
}

// ---------------------------------------------------------------------------
// GEMM variant Q: 128x64 tile, head-major Q scatter + qscale (layer-2 Q).
// ---------------------------------------------------------------------------
__global__ __launch_bounds__(256) void gemm_q_kernel(
    const short* __restrict__ A, const short* __restrict__ Bt,
    const float* __restrict__ bias, short* __restrict__ Qh, float qscale)
{
    __shared__ short As[128 * 32];
    __shared__ short Bs[64 * 32];
    const int t = threadIdx.x;
    const int wave = t >> 6, lane = t & 63;
    const int wm = wave >> 1, wn = wave & 1;
    const int m0 = blockIdx.x * 128, n0 = blockIdx.y * 64;
    const int l15 = lane & 15, l4 = lane >> 4;
    const int lrow = lane >> 2, lcol = (lane & 3) * 8;
    f32x4 acc[4][2] = {};
    for (int k0 = 0; k0 < D_DIM; k0 += 32) {
        __syncthreads();
        #pragma unroll
        for (int c = 0; c < 2; ++c) {
            int chunk = wave + c * 4;
            int row = chunk * 16 + lrow;
            GLOAD_LDS16(A + (size_t)(m0 + row) * D_DIM + k0 + lcol,
                        As + chunk * 512 + lane * 8);
        }
        {
            int row = wave * 16 + lrow;
            GLOAD_LDS16(Bt + (size_t)(n0 + row) * D_DIM + k0 + lcol,
                        Bs + wave * 512 + lane * 8);
        }
        __syncthreads();
        bf16x8 af[4], bfr[2];
        const int kq = l4 * 8;
        #pragma unroll
        for (int i = 0; i < 4; ++i)
            af[i] = *(const bf16x8*)&As[(wm * 64 + i * 16 + l15) * 32 + kq];
        #pragma unroll
        for (int j = 0; j < 2; ++j)
            bfr[j] = *(const bf16x8*)&Bs[(wn * 32 + j * 16 + l15) * 32 + kq];
        #pragma unroll
        for (int i = 0; i < 4; ++i)
            #pragma unroll
            for (int j = 0; j < 2; ++j)
                acc[i][j] = __builtin_amdgcn_mfma_f32_16x16x32_bf16(
                    af[i], bfr[j], acc[i][j], 0, 0, 0);
    }
    const int rbase = m0 + wm * 64;
    const int cbase = n0 + wn * 32;
    float bv[2];
    #pragma unroll
    for (int j = 0; j < 2; ++j) bv[j] = bias[cbase + j * 16 + l15];
    #pragma unroll
    for (int i = 0; i < 4; ++i) {
        #pragma unroll
        for (int r = 0; r < 4; ++r) {
            const int grow = rbase + i * 16 + l4 * 4 + r;
            const int b = grow >> 11, s = grow & 2047;
            #pragma unroll
            for (int j = 0; j < 2; ++j) {
                const int vcol = cbase + j * 16 + l15;
                const float v = (acc[i][j][r] + bv[j]) * qscale;
                const int h = (vcol >> 6) & 15, hd = vcol & 63;
                Qh[((size_t)(b * 16 + h) * SEQ + s) * HDIM + hd] = f2bf(v);
            }
        }
    }
}

// ---------------------------------------------------------------------------
// Swapped-QK^T MFMA flash attention body, KVBLK=128 (R20 verified).
// VSINGLE=true: 48KB; barrier before+after V_WRITE. false: 64KB dbuf.
// ---------------------------------------------------------------------------
template<bool CAUSAL, bool VSINGLE>
__device__ __forceinline__ void attn_body(
    char* ldsb,
    const short* __restrict__ Qh, const short* __restrict__ Kh,
    const short* __restrict__ Vh, short* __restrict__ O, const int id)
{
    const int t = threadIdx.x, wave = t >> 6, lane = t & 63;
    const int q_own = lane & 31, hi = lane >> 5;
    const int bh = ((id & 7) << 2) | ((id >> 3) & 3);   // XCD-local heads
    const int qsel = id >> 5;
    const int b = bh >> 4, h = bh & 15;
    const short* Qp = Qh + (size_t)bh * SEQ * HDIM;
    const short* Kp = Kh + (size_t)bh * SEQ * HDIM;
    const short* Vp = Vh + (size_t)bh * SEQ * HDIM;
    short* Op = O + (size_t)b * SEQ * D_DIM + h * HDIM;

    const int ksrc = (t & 7) ^ ((t >> 3) & 7);
    const int vr2 = (t & 31) * 2, vg = (t >> 5) * 8;
    const int swz = (q_own & 7) << 3;

    bf16x8 ones;
    #pragma unroll
    for (int j = 0; j < 8; ++j) ones[j] = (short)0x3F80;   // bf16 1.0

    const int npm = CAUSAL ? 2 : 1;
    for (int pm = 0; pm < npm; ++pm) {
        const int qt = CAUSAL ? (pm == 0 ? qsel : 15 - qsel) : qsel;
        const int q0 = qt * 128;
        const int qw = q0 + wave * 32;

        bf16x8 qf[4];
        #pragma unroll
        for (int s = 0; s < 4; ++s)
            qf[s] = *(const bf16x8*)(Qp + (size_t)(qw + q_own) * HDIM
                                     + s * 16 + hi * 8);

        int qkb[4], pvb[8], vwb[8], kgb;
        #pragma unroll
        for (int s = 0; s < 4; ++s)
            qkb[s] = q_own * 128 + 2 * ((s * 16 + hi * 8) ^ swz);
        #pragma unroll
        for (int ks = 0; ks < 8; ++ks)
            pvb[ks] = 32768 + q_own * 256 + 2 * ((ks * 16 + hi * 8) ^ swz);
        #pragma unroll
        for (int j = 0; j < 8; ++j)
            vwb[j] = 32768 + (vg + j) * 256 + 2 * (vr2 ^ (j << 3));
        kgb = t * 16;

        f32x16 oacc[2] = {};
        f32x16 lsum = {};
        float m_ = 0.0f;
        const int nkt = CAUSAL ? (qt + 1) : (SEQ / 128);

        bf16x8 va0, vb0, va1, vb1;

        if (pm) __syncthreads();

        #pragma unroll
        for (int c = 0; c < 4; ++c) {
            const int row = c * 32 + (t >> 3);
            GLOAD_LDS16(Kp + (size_t)row * HDIM + ksrc * 8,
                        ldsb + kgb + c * 4096);
        }
        va0 = *(const bf16x8*)(Vp + (size_t)vr2 * HDIM + vg);
        vb0 = *(const bf16x8*)(Vp + (size_t)(vr2 + 1) * HDIM + vg);
        va1 = *(const bf16x8*)(Vp + (size_t)(64 + vr2) * HDIM + vg);
        vb1 = *(const bf16x8*)(Vp + (size_t)(65 + vr2) * HDIM + vg);
        #pragma unroll
        for (int j = 0; j < 8; ++j) {
            unsigned int p0 = ((unsigned int)(unsigned short)vb0[j] << 16)
                            | (unsigned short)va0[j];
            unsigned int p1 = ((unsigned int)(unsigned short)vb1[j] << 16)
                            | (unsigned short)va1[j];
            *(unsigned int*)(ldsb + vwb[j])       = p0;
            *(unsigned int*)(ldsb + vwb[j] + 128) = p1;
        }
        __syncthreads();
        kgb ^= 16384;
        if (!VSINGLE) {
            #pragma unroll
            for (int j = 0; j < 8; ++j) vwb[j] ^= 16384;
        }

        for (int kt = 0; kt < nkt; ++kt) {
            const int kbase = kt * 128;
            const bool have_next = (kt + 1 < nkt);

            if (have_next) {
                #pragma unroll
                for (int c = 0; c < 4; ++c) {
                    const int row = kbase + 128 + c * 32 + (t >> 3);
                    GLOAD_LDS16(Kp + (size_t)row * HDIM + ksrc * 8,
                                ldsb + kgb + c * 4096);
                }
                va0 = *(const bf16x8*)(Vp + (size_t)(kbase + 128 + vr2) * HDIM + vg);
                vb0 = *(const bf16x8*)(Vp + (size_t)(kbase + 129 + vr2) * HDIM + vg);
                va1 = *(const bf16x8*)(Vp + (size_t)(kbase + 192 + vr2) * HDIM + vg);
                vb1 = *(const bf16x8*)(Vp + (size_t)(kbase + 193 + vr2) * HDIM + vg);
            }

            f32x16 minit;
            #pragma unroll
            for (int rr = 0; rr < 16; ++rr) minit[rr] = -m_;
            f32x16 sc[4];
            sc[0] = minit; sc[1] = minit; sc[2] = minit; sc[3] = minit;
            __builtin_amdgcn_s_setprio(1);
            #pragma unroll
            for (int kt2 = 0; kt2 < 4; ++kt2) {
                #pragma unroll
                for (int s = 0; s < 4; ++s) {
                    bf16x8 kf = *(const bf16x8*)(ldsb + qkb[s] + kt2 * 4096);
                    sc[kt2] = __builtin_amdgcn_mfma_f32_32x32x16_bf16(
                        kf, qf[s], sc[kt2], 0, 0, 0);
                }
            }
            __builtin_amdgcn_s_setprio(0);

            if (CAUSAL && (kbase + 127 > qw)) {
                #pragma unroll
                for (int kt2 = 0; kt2 < 4; ++kt2)
                    #pragma unroll
                    for (int rr = 0; rr < 16; ++rr) {
                        const int k = kbase + kt2 * 32
                                    + (rr & 3) + 8 * (rr >> 2) + 4 * hi;
                        if (k > qw + q_own) sc[kt2][rr] = -1e30f;
                    }
            }

            float km[4];
            #pragma unroll
            for (int kt2 = 0; kt2 < 4; ++kt2) {
                float t0 = fmaxf(fmaxf(sc[kt2][0],  sc[kt2][1]),  sc[kt2][2]);
                float t1 = fmaxf(fmaxf(sc[kt2][3],  sc[kt2][4]),  sc[kt2][5]);
                float t2 = fmaxf(fmaxf(sc[kt2][6],  sc[kt2][7]),  sc[kt2][8]);
                float t3 = fmaxf(fmaxf(sc[kt2][9],  sc[kt2][10]), sc[kt2][11]);
                float t4 = fmaxf(fmaxf(sc[kt2][12], sc[kt2][13]), sc[kt2][14]);
                float u  = fmaxf(fmaxf(t0, t1), t2);
                float v  = fmaxf(fmaxf(t3, t4), sc[kt2][15]);
                km[kt2] = fmaxf(u, v);
            }
            float smax = fmaxf(fmaxf(fmaxf(km[0], km[1]), km[2]), km[3]);
            smax = fmaxf(smax, __shfl_xor(smax, 32));

            if (!__all(smax <= 8.0f)) {
                const float sp = fmaxf(smax, 0.f);
                const float corr = exp2f(-sp);
                lsum[0] *= corr;
                #pragma unroll
                for (int ht = 0; ht < 2; ++ht)
                    #pragma unroll
                    for (int rr = 0; rr < 16; ++rr)
                        oacc[ht][rr] *= corr;
                #pragma unroll
                for (int kt2 = 0; kt2 < 4; ++kt2)
                    #pragma unroll
                    for (int rr = 0; rr < 16; ++rr)
                        sc[kt2][rr] -= sp;
                m_ += sp;
            }

            #pragma unroll
            for (int kt2 = 0; kt2 < 4; ++kt2)
                #pragma unroll
                for (int rr = 0; rr < 16; ++rr)
                    sc[kt2][rr] = exp2f(sc[kt2][rr]);

            u32x4 paw[8];
            #pragma unroll
            for (int kt2 = 0; kt2 < 4; ++kt2) {
                unsigned int w0a = cvtpk(sc[kt2][0],  sc[kt2][1]);
                unsigned int w0b = cvtpk(sc[kt2][2],  sc[kt2][3]);
                unsigned int w1a = cvtpk(sc[kt2][4],  sc[kt2][5]);
                unsigned int w1b = cvtpk(sc[kt2][6],  sc[kt2][7]);
                unsigned int w2a = cvtpk(sc[kt2][8],  sc[kt2][9]);
                unsigned int w2b = cvtpk(sc[kt2][10], sc[kt2][11]);
                unsigned int w3a = cvtpk(sc[kt2][12], sc[kt2][13]);
                unsigned int w3b = cvtpk(sc[kt2][14], sc[kt2][15]);
                asm("v_permlane32_swap_b32 %0, %1" : "+v"(w0a), "+v"(w1a));
                asm("v_permlane32_swap_b32 %0, %1" : "+v"(w0b), "+v"(w1b));
                asm("v_permlane32_swap_b32 %0, %1" : "+v"(w2a), "+v"(w3a));
                asm("v_permlane32_swap_b32 %0, %1" : "+v"(w2b), "+v"(w3b));
                paw[kt2 * 2 + 0][0] = w0a; paw[kt2 * 2 + 0][1] = w0b;
                paw[kt2 * 2 + 0][2] = w1a; paw[kt2 * 2 + 0][3] = w1b;
                paw[kt2 * 2 + 1][0] = w2a; paw[kt2 * 2 + 1][1] = w2b;
                paw[kt2 * 2 + 1][2] = w3a; paw[kt2 * 2 + 1][3] = w3b;
            }

            __builtin_amdgcn_s_setprio(1);
            #pragma unroll
            for (int ks = 0; ks < 8; ++ks) {
                union { u32x4 u; bf16x8 bv8; } pc;
                pc.u = paw[ks];
                bf16x8 vf0 = *(const bf16x8*)(ldsb + pvb[ks]);
                oacc[0] = __builtin_amdgcn_mfma_f32_32x32x16_bf16(
                    vf0, pc.bv8, oacc[0], 0, 0, 0);
                bf16x8 vf1 = *(const bf16x8*)(ldsb + pvb[ks] + 8192);
                oacc[1] = __builtin_amdgcn_mfma_f32_32x32x16_bf16(
                    vf1, pc.bv8, oacc[1], 0, 0, 0);
                lsum = __builtin_amdgcn_mfma_f32_32x32x16_bf16(
                    ones, pc.bv8, lsum, 0, 0, 0);
            }
            __builtin_amdgcn_s_setprio(0);

            if (have_next) {
                if (VSINGLE) __syncthreads();
                #pragma unroll
                for (int j = 0; j < 8; ++j) {
                    unsigned int p0 = ((unsigned int)(unsigned short)vb0[j] << 16)
                                    | (unsigned short)va0[j];
                    unsigned int p1 = ((unsigned int)(unsigned short)vb1[j] << 16)
                                    | (unsigned short)va1[j];
                    *(unsigned int*)(ldsb + vwb[j])       = p0;
                    *(unsigned int*)(ldsb + vwb[j] + 128) = p1;
                }
                __syncthreads();
            }
            kgb ^= 16384;
            #pragma unroll
            for (int s = 0; s < 4; ++s) qkb[s] ^= 16384;
            if (!VSINGLE) {
                #pragma unroll
                for (int ks = 0; ks < 8; ++ks) pvb[ks] ^= 16384;
                #pragma unroll
                for (int j = 0; j < 8; ++j) vwb[j] ^= 16384;
            }
        }

        const float inv = 1.0f / lsum[0];
        const int grow = qw + q_own;
        #pragma unroll
        for (int ht = 0; ht < 2; ++ht)
            #pragma unroll
            for (int j = 0; j < 4; ++j) {
                ushort4 o;
                o.x = (unsigned short)f2bf(oacc[ht][4 * j + 0] * inv);
                o.y = (unsigned short)f2bf(oacc[ht][4 * j + 1] * inv);
                o.z = (unsigned short)f2bf(oacc[ht][4 * j + 2] * inv);
                o.w = (unsigned short)f2bf(oacc[ht][4 * j + 3] * inv);
                *(ushort4*)&Op[(size_t)grow * D_DIM + ht * 32 + 8 * j + 4 * hi] = o;
            }
    }
}

// ---------------------------------------------------------------------------
// Split-KV non-causal attention: grid 1024 = 2 sp x 16 qt x 32 bh. Each block
// does 8 K-tiles (VSINGLE 48KB body) and writes unnormalized fp32 partial O
// plus per-row (l, m) for the combine pass.
// ---------------------------------------------------------------------------
__global__ __launch_bounds__(256, 2) void attn_split_kernel(
    const short* __restrict__ Qh, const short* __restrict__ Kh,
    const short* __restrict__ Vh, OPtrs op, float* __restrict__ LM)
{
    __shared__ short lds[24576];   // 48KB
    char* ldsb = (char*)lds;
    const int t = threadIdx.x, wave = t >> 6, lane = t & 63;
    const int q_own = lane & 31, hi = lane >> 5;
    const int id = blockIdx.x;
    const int bh = ((id & 7) << 2) | ((id >> 3) & 3);
    const int rest = id >> 5;               // 0..31
    const int qt = rest & 15, sp = rest >> 4;
    const short* Qp = Qh + (size_t)bh * SEQ * HDIM;
    const short* Kp = Kh + (size_t)bh * SEQ * HDIM;
    const short* Vp = Vh + (size_t)bh * SEQ * HDIM;

    const int ksrc = (t & 7) ^ ((t >> 3) & 7);
    const int vr2 = (t & 31) * 2, vg = (t >> 5) * 8;
    const int swz = (q_own & 7) << 3;
    const int kv0 = sp * 1024;              // first key row of this split

    bf16x8 ones;
    #pragma unroll
    for (int j = 0; j < 8; ++j) ones[j] = (short)0x3F80;

    const int qw = qt * 128 + wave * 32;
    bf16x8 qf[4];
    #pragma unroll
    for (int s = 0; s < 4; ++s)
        qf[s] = *(const bf16x8*)(Qp + (size_t)(qw + q_own) * HDIM
                                 + s * 16 + hi * 8);

    int qkb[4], pvb[8], vwb[8], kgb;
    #pragma unroll
    for (int s = 0; s < 4; ++s)
        qkb[s] = q_own * 128 + 2 * ((s * 16 + hi * 8) ^ swz);
    #pragma unroll
    for (int ks = 0; ks < 8; ++ks)
        pvb[ks] = 32768 + q_own * 256 + 2 * ((ks * 16 + hi * 8) ^ swz);
    #pragma unroll
    for (int j = 0; j < 8; ++j)
        vwb[j] = 32768 + (vg + j) * 256 + 2 * (vr2 ^ (j << 3));
    kgb = t * 16;

    f32x16 oacc[2] = {};
    f32x16 lsum = {};
    float m_ = 0.0f;

    bf16x8 va0, vb0, va1, vb1;

    // prologue: stage first tile of this split
    #pragma unroll
    for (int c = 0; c < 4; ++c) {
        const int row = kv0 + c * 32 + (t >> 3);
        GLOAD_LDS16(Kp + (size_t)row * HDIM + ksrc * 8, ldsb + kgb + c * 4096);
    }
    va0 = *(const bf16x8*)(Vp + (size_t)(kv0 + vr2) * HDIM + vg);
    vb0 = *(const bf16x8*)(Vp + (size_t)(kv0 + vr2 + 1) * HDIM + vg);
    va1 = *(const bf16x8*)(Vp + (size_t)(kv0 + 64 + vr2) * HDIM + vg);
    vb1 = *(const bf16x8*)(Vp + (size_t)(kv0 + 65 + vr2) * HDIM + vg);
    #pragma unroll
    for (int j = 0; j < 8; ++j) {
        unsigned int p0 = ((unsigned int)(unsigned short)vb0[j] << 16)
                        | (unsigned short)va0[j];
        unsigned int p1 = ((unsigned int)(unsigned short)vb1[j] << 16)
                        | (unsigned short)va1[j];
        *(unsigned int*)(ldsb + vwb[j])       = p0;
        *(unsigned int*)(ldsb + vwb[j] + 128) = p1;
    }
    __syncthreads();
    kgb ^= 16384;                          // K write side -> buf1 (V single)

    for (int kt = 0; kt < 8; ++kt) {
        const int kbase = kv0 + kt * 128;
        const bool have_next = (kt + 1 < 8);

        if (have_next) {
            #pragma unroll
            for (int c = 0; c < 4; ++c) {
                const int row = kbase + 128 + c * 32 + (t >> 3);
                GLOAD_LDS16(Kp + (size_t)row * HDIM + ksrc * 8,
                            ldsb + kgb + c * 4096);
            }
            va0 = *(const bf16x8*)(Vp + (size_t)(kbase + 128 + vr2) * HDIM + vg);
            vb0 = *(const bf16x8*)(Vp + (size_t)(kbase + 129 + vr2) * HDIM + vg);
            va1 = *(const bf16x8*)(Vp + (size_t)(kbase + 192 + vr2) * HDIM + vg);
            vb1 = *(const bf16x8*)(Vp + (size_t)(kbase + 193 + vr2) * HDIM + vg);
        }

        f32x16 minit;
        #pragma unroll
        for (int rr = 0; rr < 16; ++rr) minit[rr] = -m_;
        f32x16 sc[4];
        sc[0] = minit; sc[1] = minit; sc[2] = minit; sc[3] = minit;
        __builtin_amdgcn_s_setprio(1);
        #pragma unroll
        for (int kt2 = 0; kt2 < 4; ++kt2) {
            #pragma unroll
            for (int s = 0; s < 4; ++s) {
                bf16x8 kf = *(const bf16x8*)(ldsb + qkb[s] + kt2 * 4096);
                sc[kt2] = __builtin_amdgcn_mfma_f32_32x32x16_bf16(
                    kf, qf[s], sc[kt2], 0, 0, 0);
            }
        }
        __builtin_amdgcn_s_setprio(0);

        float km[4];
        #pragma unroll
        for (int kt2 = 0; kt2 < 4; ++kt2) {
            float t0 = fmaxf(fmaxf(sc[kt2][0],  sc[kt2][1]),  sc[kt2][2]);
            float t1 = fmaxf(fmaxf(sc[kt2][3],  sc[kt2][4]),  sc[kt2][5]);
            float t2 = fmaxf(fmaxf(sc[kt2][6],  sc[kt2][7]),  sc[kt2][8]);
            float t3 = fmaxf(fmaxf(sc[kt2][9],  sc[kt2][10]), sc[kt2][11]);
            float t4 = fmaxf(fmaxf(sc[kt2][12], sc[kt2][13]), sc[kt2][14]);
            float u  = fmaxf(fmaxf(t0, t1), t2);
            float v  = fmaxf(fmaxf(t3, t4), sc[kt2][15]);
            km[kt2] = fmaxf(u, v);
        }
        float smax = fmaxf(fmaxf(fmaxf(km[0], km[1]), km[2]), km[3]);
        smax = fmaxf(smax, __shfl_xor(smax, 32));

        if (!__all(smax <= 8.0f)) {
            const float spv = fmaxf(smax, 0.f);
            const float corr = exp2f(-spv);
            lsum[0] *= corr;
            #pragma unroll
            for (int ht = 0; ht < 2; ++ht)
                #pragma unroll
                for (int rr = 0; rr < 16; ++rr)
                    oacc[ht][rr] *= corr;
            #pragma unroll
            for (int kt2 = 0; kt2 < 4; ++kt2)
                #pragma unroll
                for (int rr = 0; rr < 16; ++rr)
                    sc[kt2][rr] -= spv;
            m_ += spv;
        }

        #pragma unroll
        for (int kt2 = 0; kt2 < 4; ++kt2)
            #pragma unroll
            for (int rr = 0; rr < 16; ++rr)
                sc[kt2][rr] = exp2f(sc[kt2][rr]);

        u32x4 paw[8];
        #pragma unroll
        for (int kt2 = 0; kt2 < 4; ++kt2) {
            unsigned int w0a = cvtpk(sc[kt2][0],  sc[kt2][1]);
            unsigned int w0b = cvtpk(sc[kt2][2],  sc[kt2][3]);
            unsigned int w1a = cvtpk(sc[kt2][4],  sc[kt2][5]);
            unsigned int w1b = cvtpk(sc[kt2][6],  sc[kt2][7]);
            unsigned int w2a = cvtpk(sc[kt2][8],  sc[kt2][9]);
            unsigned int w2b = cvtpk(sc[kt2][10], sc[kt2][11]);
            unsigned int w3a = cvtpk(sc[kt2][12], sc[kt2][13]);
            unsigned int w3b = cvtpk(sc[kt2][14], sc[kt2][15]);
            asm("v_permlane32_swap_b32 %0, %1" : "+v"(w0a), "+v"(w1a));
            asm("v_permlane32_swap_b32 %0, %1" : "+v"(w0b), "+v"(w1b));
            asm("v_permlane32_swap_b32 %0, %1" : "+v"(w2a), "+v"(w3a));
            asm("v_permlane32_swap_b32 %0, %1" : "+v"(w2b), "+v"(w3b));
            paw[kt2 * 2 + 0][0] = w0a; paw[kt2 * 2 + 0][1] = w0b;
            paw[kt2 * 2 + 0][2] = w1a; paw[kt2 * 2 + 0][3] = w1b;
            paw[kt2 * 2 + 1][0] = w2a; paw[kt2 * 2 + 1][1] = w2b;
            paw[kt2 * 2 + 1][2] = w3a; paw[kt2 * 2 + 1][3] = w3b;
        }

        __builtin_amdgcn_s_setprio(1);
        #pragma unroll
        for (int ks = 0; ks < 8; ++ks) {
            union { u32x4 u; bf16x8 bv8; } pc;
            pc.u = paw[ks];
            bf16x8 vf0 = *(const bf16x8*)(ldsb + pvb[ks]);
            oacc[0] = __builtin_amdgcn_mfma_f32_32x32x16_bf16(
                vf0, pc.bv8, oacc[0], 0, 0, 0);
            bf16x8 vf1 = *(const bf16x8*)(ldsb + pvb[ks] + 8192);
            oacc[1] = __builtin_amdgcn_mfma_f32_32x32x16_bf16(
                vf1, pc.bv8, oacc[1], 0, 0, 0);
            lsum = __builtin_amdgcn_mfma_f32_32x32x16_bf16(
                ones, pc.bv8, lsum, 0, 0, 0);
        }
        __builtin_amdgcn_s_setprio(0);

        if (have_next) {
            __syncthreads();           // PV reads done; drains gll
            #pragma unroll
            for (int j = 0; j < 8; ++j) {
                unsigned int p0 = ((unsigned int)(unsigned short)vb0[j] << 16)
                                | (unsigned short)va0[j];
                unsigned int p1 = ((unsigned int)(unsigned short)vb1[j] << 16)
                                | (unsigned short)va1[j];
                *(unsigned int*)(ldsb + vwb[j])       = p0;
                *(unsigned int*)(ldsb + vwb[j] + 128) = p1;
            }
            __syncthreads();
        }
        kgb ^= 16384;
        #pragma unroll
        for (int s = 0; s < 4; ++s) qkb[s] ^= 16384;
    }

    // partial epilogue: unnormalized fp32 O + (l, m)
    float* Osp = op.p[sp * 2 + (bh >> 4)]
               + (size_t)(bh & 15) * SEQ * HDIM;
    const int grow = qw + q_own;
    #pragma unroll
    for (int ht = 0; ht < 2; ++ht)
        #pragma unroll
        for (int j = 0; j < 4; ++j) {
            float4 o4 = make_float4(oacc[ht][4 * j + 0], oacc[ht][4 * j + 1],
                                    oacc[ht][4 * j + 2], oacc[ht][4 * j + 3]);
            *(float4*)&Osp[(size_t)grow * HDIM + ht * 32 + 8 * j + 4 * hi] = o4;
        }
    if (hi == 0) {
        float2 lm2 = make_float2(lsum[0], m_);
        *(float2*)&LM[(((size_t)sp * 32 + bh) * SEQ + grow) * 2] = lm2;
    }
}

// ---------------------------------------------------------------------------
// Combine: O = (O1*2^(m1-m) + O2*2^(m2-m)) / (l1*2^(m1-m) + l2*2^(m2-m)).
// Grid 2048 x 256; thread handles 8 hd of one (bh, q).
// ---------------------------------------------------------------------------
__global__ __launch_bounds__(256) void attn_combine_kernel(
    OPtrs op, const float* __restrict__ LM, short* __restrict__ O)
{
    const int idx = blockIdx.x * 256 + threadIdx.x;   // 0..524287
    const int hd8 = (idx & 7) * 8;
    const int q   = (idx >> 3) & 2047;
    const int bh  = idx >> 14;
    const int b = bh >> 4, h = bh & 15;
    const float2 lm1 = *(const float2*)&LM[(((size_t)0 * 32 + bh) * SEQ + q) * 2];
    const float2 lm2 = *(const float2*)&LM[(((size_t)1 * 32 + bh) * SEQ + q) * 2];
    const float m  = fmaxf(lm1.y, lm2.y);
    const float w1 = exp2f(lm1.y - m), w2 = exp2f(lm2.y - m);
    const float inv = 1.0f / (lm1.x * w1 + lm2.x * w2);
    const float* O1 = op.p[0 + (bh >> 4)]
                    + ((size_t)(bh & 15) * SEQ + q) * HDIM + hd8;
    const float* O2 = op.p[2 + (bh >> 4)]
                    + ((size_t)(bh & 15) * SEQ + q) * HDIM + hd8;
    float4 a0 = *(const float4*)O1, a1 = *(const float4*)(O1 + 4);
    float4 b0 = *(const float4*)O2, b1 = *(const float4*)(O2 + 4);
    short* dst = O + ((size_t)b * SEQ + q) * D_DIM + h * HDIM + hd8;
    ushort4 r0, r1;
    r0.x = (unsigned short)f2bf((a0.x * w1 + b0.x * w2) * inv);
    r0.y = (unsigned short)f2bf((a0.y * w1 + b0.y * w2) * inv);
    r0.z = (unsigned short)f2bf((a0.z * w1 + b0.z * w2) * inv);
    r0.w = (unsigned short)f2bf((a0.w * w1 + b0.w * w2) * inv);
    r1.x = (unsigned short)f2bf((a1.x * w1 + b1.x * w2) * inv);
    r1.y = (unsigned short)f2bf((a1.y * w1 + b1.y * w2) * inv);
    r1.z = (unsigned short)f2bf((a1.z * w1 + b1.z * w2) * inv);
    r1.w = (unsigned short)f2bf((a1.w * w1 + b1.w * w2) * inv);
    *(ushort4*)dst       = r0;
    *(ushort4*)(dst + 4) = r1;
}

// Fused: blocks 0..255 = causal attention (VSINGLE 48KB); 256..767 = K2/V2.
__global__ __launch_bounds__(256, 2) void fused_cattn_kv2_kernel(
    const short* __restrict__ Qh, const short* __restrict__ Kh,
    const short* __restrict__ Vh, short* __restrict__ O,
    const short* __restrict__ A2, const short* __restrict__ Bt2,
    const float* __restrict__ bias2,
    short* __restrict__ Kh2, short* __restrict__ Vh2)
{
    __shared__ short lds[24576];   // 48KB
    if (blockIdx.x < 256) {
        attn_body<true, true>((char*)lds, Qh, Kh, Vh, O, blockIdx.x);
    } else {
        const int bx2 = blockIdx.x - 256;        // 512 blocks: (32 m) x (16 n)
        gemm_qkv_body(lds, lds + 4096, A2, Bt2, bias2,
                      nullptr, Kh2, Vh2, 1024, 1.0f, bx2 & 31, bx2 >> 5);
    }
}

// ---------------------------------------------------------------------------
// LayerNorm rows of 1024; optional bf16 side output. In-place safe.
// ---------------------------------------------------------------------------
__global__ __launch_bounds__(256) void ln_kernel(
    const float* __restrict__ X, const float* __restrict__ g,
    const float* __restrict__ bb, float* __restrict__ outf,
    short* __restrict__ outb)
{
    const int row = blockIdx.x;
    const int t = threadIdx.x;
    const float* x = X + (size_t)row * D_DIM;
    float4 v = *(const float4*)(x + (t << 2));
    float s  = v.x + v.y + v.z + v.w;
    float sq = v.x * v.x + v.y * v.y + v.z * v.z + v.w * v.w;
    #pragma unroll
    for (int off = 1; off < 64; off <<= 1) {
        s  += __shfl_xor(s, off);
        sq += __shfl_xor(sq, off);
    }
    __shared__ float ss[4], ssq[4];
    const int wid = t >> 6, lane = t & 63;
    if (lane == 0) { ss[wid] = s; ssq[wid] = sq; }
    __syncthreads();
    s  = ss[0] + ss[1] + ss[2] + ss[3];
    sq = ssq[0] + ssq[1] + ssq[2] + ssq[3];
    const float mean = s * (1.0f / 1024.0f);
    const float var  = sq * (1.0f / 1024.0f) - mean * mean;
    const float inv  = rsqrtf(var + 1e-5f);
    float4 gv = *(const float4*)(g  + (t << 2));
    float4 bv = *(const float4*)(bb + (t << 2));
    float4 o;
    o.x = gv.x * (v.x - mean) * inv + bv.x;
    o.y = gv.y * (v.y - mean) * inv + bv.y;
    o.z = gv.z * (v.z - mean) * inv + bv.z;
    o.w = gv.w * (v.w - mean) * inv + bv.w;
    if (outf) *(float4*)(outf + (size_t)row * D_DIM + (t << 2)) = o;
    if (outb) {
        ushort4 ob;
        ob.x = (unsigned short)f2bf(o.x); ob.y = (unsigned short)f2bf(o.y);
        ob.z = (unsigned short)f2bf(o.z); ob.w = (unsigned short)f2bf(o.w);
        *(ushort4*)(outb + (size_t)row * D_DIM + (t << 2)) = ob;
    }
}

// ---------------------------------------------------------------------------
extern "C" void kernel_launch(void* const* d_in, const int* in_sizes, int n_in,
                              void* d_out, int out_size, void* d_ws, size_t ws_size,
                              hipStream_t stream)
{
    (void)in_sizes; (void)n_in; (void)out_size; (void)ws_size;
    const float* S0f = (const float*)d_in[0];
    const float* Hf  = (const float*)d_in[1];
    const float* bq1 = (const float*)d_in[3];
    const float* bk1 = (const float*)d_in[5];
    const float* bv1 = (const float*)d_in[7];
    const float* bo1 = (const float*)d_in[9];
    const float* g1  = (const float*)d_in[10]; const float* b1 = (const float*)d_in[11];
    const float* bq2 = (const float*)d_in[13];
    const float* bk2 = (const float*)d_in[15];
    const float* bv2 = (const float*)d_in[17];
    const float* bo2 = (const float*)d_in[19];
    const float* g2  = (const float*)d_in[20]; const float* b2 = (const float*)d_in[21];
    const float* bff = (const float*)d_in[23];
    const float* g3  = (const float*)d_in[24]; const float* b3 = (const float*)d_in[25];

    char* ws = (char*)d_ws;
    size_t off = 0;
    auto alloc = [&](size_t bytes) { char* p = ws + off; off += (bytes + 255) & ~(size_t)255; return p; };
    short* Wt   = (short*)alloc((size_t)9 * D_DIM * D_DIM * 2);   // 18 MB
    short* bS0  = (short*)alloc((size_t)MROWS * D_DIM * 2);       // 8 MB (dead after QKV1 -> Opart)
    short* bH   = (short*)alloc((size_t)MROWS * D_DIM * 2);       // 8 MB (dead after fused -> Opart)
    short* Qhb  = (short*)alloc((size_t)MROWS * D_DIM * 2);       // 8 MB head-major
    short* Khb  = (short*)alloc((size_t)MROWS * D_DIM * 2);       // 8 MB (dead after fused -> Opart)
    short* Vhb  = (short*)alloc((size_t)MROWS * D_DIM * 2);       // 8 MB (dead after fused -> Opart)
    short* Khb2 = (short*)alloc((size_t)MROWS * D_DIM * 2);       // 8 MB (L2 K)
    short* Vhb2 = (short*)alloc((size_t)MROWS * D_DIM * 2);       // 8 MB (L2 V)
    short* bAO  = (short*)alloc((size_t)MROWS * D_DIM * 2);       // 8 MB
    float* X    = (float*)alloc((size_t)MROWS * D_DIM * 4);       // 16 MB
    short* bSx  = (short*)alloc((size_t)MROWS * D_DIM * 2);       // 8 MB
    float* cb1  = (float*)alloc(3072 * 4);
    float* cb2  = (float*)alloc(2048 * 4);
    float* LM   = (float*)alloc((size_t)2 * 32 * SEQ * 2 * 4);    // 1 MB

    const size_t WSTRIDE = (size_t)D_DIM * D_DIM;
    const float QSCALE = 0.125f * 1.44269504088896f;   // 1/sqrt(64) * log2(e)

    WPtrs wp;
    wp.p[0] = (const float*)d_in[2];   // Wq1
    wp.p[1] = (const float*)d_in[4];   // Wk1
    wp.p[2] = (const float*)d_in[6];   // Wv1
    wp.p[3] = (const float*)d_in[8];   // Wo1
    wp.p[4] = (const float*)d_in[12];  // Wq2
    wp.p[5] = (const float*)d_in[14];  // Wk2
    wp.p[6] = (const float*)d_in[16];  // Wv2
    wp.p[7] = (const float*)d_in[18];  // Wo2
    wp.p[8] = (const float*)d_in[22];  // Wf

    // Split-KV partials reuse dead bf16 buffers (each 8MB = 16 heads x 2048 x 64 fp32)
    OPtrs op;
    op.p[0] = (float*)bS0;   // sp0, bh  0..15
    op.p[1] = (float*)bH;    // sp0, bh 16..31
    op.p[2] = (float*)Khb;   // sp1, bh  0..15
    op.p[3] = (float*)Vhb;   // sp1, bh 16..31

    prep_kernel<<<dim3(6420), 256, 0, stream>>>(
        wp, Wt, S0f, Hf, bS0, bH, bq1, bk1, bv1, bk2, bv2, cb1, cb2);

    const dim3 blk(256);
    const dim3 resid_grid(32, 16);           // 128x64 tiles, 512 blocks

    // ---- layer 1: causal self-attention (fused with K2/V2 projection) ----
    gemm_qkv_kernel<<<dim3(32, 24), blk, 0, stream>>>(
        bS0, Wt, cb1, Qhb, Khb, Vhb, 0, QSCALE);
    fused_cattn_kv2_kernel<<<dim3(768), blk, 0, stream>>>(
        Qhb, Khb, Vhb, bAO, bH, Wt + 5 * WSTRIDE, cb2, Khb2, Vhb2);
    gemm_resid_kernel<<<resid_grid, blk, 0, stream>>>(
        bAO, Wt + 3 * WSTRIDE, bo1, S0f, X);
    ln_kernel<<<MROWS, blk, 0, stream>>>(X, g1, b1, X, bSx);

    // ---- layer 2: cross-attention over H (2-way split-KV) ----
    gemm_q_kernel<<<resid_grid, blk, 0, stream>>>(
        bSx, Wt + 4 * WSTRIDE, bq2, Qhb, QSCALE);
    attn_split_kernel<<<dim3(1024), blk, 0, stream>>>(
        Qhb, Khb2, Vhb2, op, LM);
    attn_combine_kernel<<<dim3(2048), blk, 0, stream>>>(op, LM, bAO);
    gemm_resid_kernel<<<resid_grid, blk, 0, stream>>>(
        bAO, Wt + 7 * WSTRIDE, bo2, X, X);
    ln_kernel<<<MROWS, blk, 0, stream>>>(X, g2, b2, X, bSx);

    // ---- FFN ----
    gemm_resid_kernel<<<resid_grid, blk, 0, stream>>>(
        bSx, Wt + 8 * WSTRIDE, bff, X, X);
    ln_kernel<<<MROWS, blk, 0, stream>>>(X, g3, b3, (float*)d_out, nullptr);
}

// Round 22
// 267.721 us; speedup vs baseline: 1.0363x; 1.0363x over previous
//
#include <hip/hip_runtime.h>
#include <hip/hip_bf16.h>
#include <cstdint>
#include <cstddef>

// Decoder cell: B=2, S=T=2048, D=1024, H=16, HD=64.
// Round 22: exact restore of R20 (verified best, 267.8us). R21's split-KV
// regressed (straggler tail at grid 1024 w/ 3-block residency + 2x partial
// output bytes; split kernel 72.7us > unsplit 70us). Final configuration:
//  - bf16 MFMA everywhere; fp32 residual stream
//  - fused prep (transpose/convert/bias-concat, 1 dispatch)
//  - QKV1 128x128 GEMM -> head-major Q/K/V + folded softmax scale
//  - fused dispatch: causal attn (VSINGLE 48KB) + K2/V2 projection
//  - attention: swapped-QK^T 32x32 MFMA, KVBLK=128, softmax-on-MFMA
//    (C=-m_ preshift + ones-MFMA row-sum), hoisted lane-constant LDS addrs,
//    XCD remap, permlane32 P-packing, defer-max; causal pair load-balance
//  - non-causal attn standalone (64KB V-dbuf)
//  - out-proj/FFN/Q2 GEMMs at 128x64 tiles (2 blocks/CU)

#define D_DIM 1024
#define SEQ   2048
#define NHEAD 16
#define HDIM  64
#define MROWS 4096

typedef __attribute__((ext_vector_type(8)))  short bf16x8;
typedef __attribute__((ext_vector_type(4)))  float f32x4;
typedef __attribute__((ext_vector_type(16))) float f32x16;
typedef __attribute__((ext_vector_type(4)))  unsigned int u32x4;

static __device__ __forceinline__ short f2bf(float x) {
    __hip_bfloat16 h = __float2bfloat16(x);
    return *reinterpret_cast<short*>(&h);
}

static __device__ __forceinline__ unsigned int cvtpk(float lo, float hi2) {
    unsigned int r;
    asm("v_cvt_pk_bf16_f32 %0, %1, %2" : "=v"(r) : "v"(lo), "v"(hi2));
    return r;
}

#define GLOAD_LDS16(g, l)                                                     \
    __builtin_amdgcn_global_load_lds(                                         \
        (const __attribute__((address_space(1))) unsigned int*)(g),           \
        (__attribute__((address_space(3))) unsigned int*)(l), 16, 0, 0)

// ---------------------------------------------------------------------------
// Fused prep: weight transpose+convert (blocks 0..2303), fp32->bf16 convert
// of S0/H (2304..6399), bias concat (6400..6419). All independent.
// ---------------------------------------------------------------------------
struct WPtrs { const float* p[9]; };

__global__ __launch_bounds__(256) void prep_kernel(
    WPtrs wp, short* __restrict__ Wt,
    const float* __restrict__ s0, const float* __restrict__ hx,
    short* __restrict__ d0, short* __restrict__ d1,
    const float* __restrict__ bq1, const float* __restrict__ bk1,
    const float* __restrict__ bv1, const float* __restrict__ bk2,
    const float* __restrict__ bv2, float* __restrict__ cb1,
    float* __restrict__ cb2)
{
    __shared__ float tl[64][65];
    const int t = threadIdx.x;
    const int id = blockIdx.x;
    if (id < 2304) {
        const int z = id >> 8, rem = id & 255;
        const float* src = wp.p[z];
        short* dst = Wt + (size_t)z * D_DIM * D_DIM;
        const int r0 = (rem >> 4) * 64;
        const int c0 = (rem & 15) * 64;
        #pragma unroll
        for (int i = 0; i < 4; ++i) {
            int row = i * 16 + (t >> 4);
            int col = (t & 15) * 4;
            float4 v = *(const float4*)(src + (size_t)(r0 + row) * D_DIM + c0 + col);
            tl[row][col + 0] = v.x; tl[row][col + 1] = v.y;
            tl[row][col + 2] = v.z; tl[row][col + 3] = v.w;
        }
        __syncthreads();
        #pragma unroll
        for (int i = 0; i < 4; ++i) {
            int nrow = i * 16 + (t >> 4);
            int kcol = (t & 15) * 4;
            ushort4 o;
            o.x = (unsigned short)f2bf(tl[kcol + 0][nrow]);
            o.y = (unsigned short)f2bf(tl[kcol + 1][nrow]);
            o.z = (unsigned short)f2bf(tl[kcol + 2][nrow]);
            o.w = (unsigned short)f2bf(tl[kcol + 3][nrow]);
            *(ushort4*)(dst + (size_t)(c0 + nrow) * D_DIM + r0 + kcol) = o;
        }
    } else if (id < 6400) {
        const int cid = id - 2304;
        const bool second = cid >= 2048;
        const float* src = second ? hx : s0;
        short* dst = second ? d1 : d0;
        size_t i = ((size_t)(cid - (second ? 2048 : 0)) * 256 + t) * 8;
        float4 a = *(const float4*)(src + i);
        float4 b = *(const float4*)(src + i + 4);
        bf16x8 o;
        o[0] = f2bf(a.x); o[1] = f2bf(a.y); o[2] = f2bf(a.z); o[3] = f2bf(a.w);
        o[4] = f2bf(b.x); o[5] = f2bf(b.y); o[6] = f2bf(b.z); o[7] = f2bf(b.w);
        *(bf16x8*)(dst + i) = o;
    } else {
        const int i = (id - 6400) * 256 + t;
        if      (i < 1024) cb1[i] = bq1[i];
        else if (i < 2048) cb1[i] = bk1[i - 1024];
        else if (i < 3072) cb1[i] = bv1[i - 2048];
        else if (i < 4096) cb2[i - 3072] = bk2[i - 3072];
        else               cb2[i - 3072] = bv2[i - 4096];
    }
}

// ---------------------------------------------------------------------------
// QKV-projection GEMM body: 128x128 tile, BK=32, 4 waves, 16x16x32 MFMA.
// ---------------------------------------------------------------------------
__device__ __forceinline__ void gemm_qkv_body(
    short* __restrict__ As_, short* __restrict__ Bs_,
    const short* __restrict__ A, const short* __restrict__ Bt,
    const float* __restrict__ bias,
    short* __restrict__ Qh, short* __restrict__ Kh, short* __restrict__ Vh,
    int col0, float qscale, int bx, int by)
{
    const int t = threadIdx.x;
    const int wave = t >> 6, lane = t & 63;
    const int wm = wave >> 1, wn = wave & 1;
    const int m0 = bx * 128, n0 = by * 128;
    const int l15 = lane & 15, l4 = lane >> 4;
    const int lrow = lane >> 2, lcol = (lane & 3) * 8;
    f32x4 acc[4][4] = {};
    for (int k0 = 0; k0 < D_DIM; k0 += 32) {
        __syncthreads();
        #pragma unroll
        for (int c = 0; c < 2; ++c) {
            int chunk = wave + c * 4;
            int row = chunk * 16 + lrow;
            GLOAD_LDS16(A  + (size_t)(m0 + row) * D_DIM + k0 + lcol,
                        As_ + chunk * 512 + lane * 8);
            GLOAD_LDS16(Bt + (size_t)(n0 + row) * D_DIM + k0 + lcol,
                        Bs_ + chunk * 512 + lane * 8);
        }
        __syncthreads();
        bf16x8 af[4], bfr[4];
        const int kq = l4 * 8;
        #pragma unroll
        for (int i = 0; i < 4; ++i)
            af[i] = *(const bf16x8*)&As_[(wm * 64 + i * 16 + l15) * 32 + kq];
        #pragma unroll
        for (int j = 0; j < 4; ++j)
            bfr[j] = *(const bf16x8*)&Bs_[(wn * 64 + j * 16 + l15) * 32 + kq];
        #pragma unroll
        for (int i = 0; i < 4; ++i)
            #pragma unroll
            for (int j = 0; j < 4; ++j)
                acc[i][j] = __builtin_amdgcn_mfma_f32_16x16x32_bf16(
                    af[i], bfr[j], acc[i][j], 0, 0, 0);
    }
    const int rbase = m0 + wm * 64;
    const int cbase = n0 + wn * 64;
    float bv[4];
    #pragma unroll
    for (int j = 0; j < 4; ++j) bv[j] = bias[cbase + j * 16 + l15];
    #pragma unroll
    for (int i = 0; i < 4; ++i) {
        #pragma unroll
        for (int r = 0; r < 4; ++r) {
            const int grow = rbase + i * 16 + l4 * 4 + r;
            const int b = grow >> 11, s = grow & 2047;
            #pragma unroll
            for (int j = 0; j < 4; ++j) {
                const int vcol = col0 + cbase + j * 16 + l15;
                float v = acc[i][j][r] + bv[j];
                if (vcol < 1024) v *= qscale;
                short* dst = (vcol < 1024) ? Qh : ((vcol < 2048) ? Kh : Vh);
                const int h = (vcol >> 6) & 15, hd = vcol & 63;
                dst[((size_t)(b * 16 + h) * SEQ + s) * HDIM + hd] = f2bf(v);
            }
        }
    }
}

__global__ __launch_bounds__(256) void gemm_qkv_kernel(
    const short* __restrict__ A, const short* __restrict__ Bt,
    const float* __restrict__ bias,
    short* __restrict__ Qh, short* __restrict__ Kh, short* __restrict__ Vh,
    int col0, float qscale)
{
    __shared__ short lds[8192];
    gemm_qkv_body(lds, lds + 4096, A, Bt, bias, Qh, Kh, Vh,
                  col0, qscale, blockIdx.x, blockIdx.y);
}

// ---------------------------------------------------------------------------
// GEMM variant A: 128x64 tile, fp32 output + residual (out-proj / FFN).
// ---------------------------------------------------------------------------
__global__ __launch_bounds__(256) void gemm_resid_kernel(
    const short* __restrict__ A, const short* __restrict__ Bt,
    const float* __restrict__ bias, const float* __restrict__ resid,
    float* __restrict__ Cout)
{
    __shared__ short As[128 * 32];
    __shared__ short Bs[64 * 32];
    const int t = threadIdx.x;
    const int wave = t >> 6, lane = t & 63;
    const int wm = wave >> 1, wn = wave & 1;
    const int m0 = blockIdx.x * 128, n0 = blockIdx.y * 64;
    const int l15 = lane & 15, l4 = lane >> 4;
    const int lrow = lane >> 2, lcol = (lane & 3) * 8;
    f32x4 acc[4][2] = {};
    for (int k0 = 0; k0 < D_DIM; k0 += 32) {
        __syncthreads();
        #pragma unroll
        for (int c = 0; c < 2; ++c) {
            int chunk = wave + c * 4;
            int row = chunk * 16 + lrow;
            GLOAD_LDS16(A + (size_t)(m0 + row) * D_DIM + k0 + lcol,
                        As + chunk * 512 + lane * 8);
        }
        {
            int row = wave * 16 + lrow;
            GLOAD_LDS16(Bt + (size_t)(n0 + row) * D_DIM + k0 + lcol,
                        Bs + wave * 512 + lane * 8);
        }
        __syncthreads();
        bf16x8 af[4], bfr[2];
        const int kq = l4 * 8;
        #pragma unroll
        for (int i = 0; i < 4; ++i)
            af[i] = *(const bf16x8*)&As[(wm * 64 + i * 16 + l15) * 32 + kq];
        #pragma unroll
        for (int j = 0; j < 2; ++j)
            bfr[j] = *(const bf16x8*)&Bs[(wn * 32 + j * 16 + l15) * 32 + kq];
        #pragma unroll
        for (int i = 0; i < 4; ++i)
            #pragma unroll
            for (int j = 0; j < 2; ++j)
                acc[i][j] = __builtin_amdgcn_mfma_f32_16x16x32_bf16(
                    af[i], bfr[j], acc[i][j], 0, 0, 0);
    }
    const int rbase = m0 + wm * 64;
    const int cbase = n0 + wn * 32;
    float bv[2];
    #pragma unroll
    for (int j = 0; j < 2; ++j) bv[j] = bias[cbase + j * 16 + l15];
    #pragma unroll
    for (int i = 0; i < 4; ++i) {
        #pragma unroll
        for (int r = 0; r < 4; ++r) {
            const int grow = rbase + i * 16 + l4 * 4 + r;
            #pragma unroll
            for (int j = 0; j < 2; ++j) {
                const int gcol = cbase + j * 16 + l15;
                float v = acc[i][j][r] + bv[j]
                        + resid[(size_t)grow * D_DIM + gcol];
                Cout[(size_t)grow * D_DIM + gcol] = v;
            }
        }
    }
}

// ---------------------------------------------------------------------------
// GEMM variant Q: 128x64 tile, head-major Q scatter + qscale (layer-2 Q).
// ---------------------------------------------------------------------------
__global__ __launch_bounds__(256) void gemm_q_kernel(
    const short* __restrict__ A, const short* __restrict__ Bt,
    const float* __restrict__ bias, short* __restrict__ Qh, float qscale)
{
    __shared__ short As[128 * 32];
    __shared__ short Bs[64 * 32];
    const int t = threadIdx.x;
    const int wave = t >> 6, lane = t & 63;
    const int wm = wave >> 1, wn = wave & 1;
    const int m0 = blockIdx.x * 128, n0 = blockIdx.y * 64;
    const int l15 = lane & 15, l4 = lane >> 4;
    const int lrow = lane >> 2, lcol = (lane & 3) * 8;
    f32x4 acc[4][2] = {};
    for (int k0 = 0; k0 < D_DIM; k0 += 32) {
        __syncthreads();
        #pragma unroll
        for (int c = 0; c < 2; ++c) {
            int chunk = wave + c * 4;
            int row = chunk * 16 + lrow;
            GLOAD_LDS16(A + (size_t)(m0 + row) * D_DIM + k0 + lcol,
                        As + chunk * 512 + lane * 8);
        }
        {
            int row = wave * 16 + lrow;
            GLOAD_LDS16(Bt + (size_t)(n0 + row) * D_DIM + k0 + lcol,
                        Bs + wave * 512 + lane * 8);
        }
        __syncthreads();
        bf16x8 af[4], bfr[2];
        const int kq = l4 * 8;
        #pragma unroll
        for (int i = 0; i < 4; ++i)
            af[i] = *(const bf16x8*)&As[(wm * 64 + i * 16 + l15) * 32 + kq];
        #pragma unroll
        for (int j = 0; j < 2; ++j)
            bfr[j] = *(const bf16x8*)&Bs[(wn * 32 + j * 16 + l15) * 32 + kq];
        #pragma unroll
        for (int i = 0; i < 4; ++i)
            #pragma unroll
            for (int j = 0; j < 2; ++j)
                acc[i][j] = __builtin_amdgcn_mfma_f32_16x16x32_bf16(
                    af[i], bfr[j], acc[i][j], 0, 0, 0);
    }
    const int rbase = m0 + wm * 64;
    const int cbase = n0 + wn * 32;
    float bv[2];
    #pragma unroll
    for (int j = 0; j < 2; ++j) bv[j] = bias[cbase + j * 16 + l15];
    #pragma unroll
    for (int i = 0; i < 4; ++i) {
        #pragma unroll
        for (int r = 0; r < 4; ++r) {
            const int grow = rbase + i * 16 + l4 * 4 + r;
            const int b = grow >> 11, s = grow & 2047;
            #pragma unroll
            for (int j = 0; j < 2; ++j) {
                const int vcol = cbase + j * 16 + l15;
                const float v = (acc[i][j][r] + bv[j]) * qscale;
                const int h = (vcol >> 6) & 15, hd = vcol & 63;
                Qh[((size_t)(b * 16 + h) * SEQ + s) * HDIM + hd] = f2bf(v);
            }
        }
    }
}

// ---------------------------------------------------------------------------
// Swapped-QK^T MFMA flash attention body, KVBLK=128.
// VSINGLE=true: V single-buffered (48KB; barrier before+after V_WRITE).
// VSINGLE=false: 64KB V double-buffer. Softmax-on-MFMA; hoisted LDS addrs.
// ---------------------------------------------------------------------------
template<bool CAUSAL, bool VSINGLE>
__device__ __forceinline__ void attn_body(
    char* ldsb,
    const short* __restrict__ Qh, const short* __restrict__ Kh,
    const short* __restrict__ Vh, short* __restrict__ O, const int id)
{
    const int t = threadIdx.x, wave = t >> 6, lane = t & 63;
    const int q_own = lane & 31, hi = lane >> 5;
    const int bh = ((id & 7) << 2) | ((id >> 3) & 3);   // XCD-local heads
    const int qsel = id >> 5;
    const int b = bh >> 4, h = bh & 15;
    const short* Qp = Qh + (size_t)bh * SEQ * HDIM;
    const short* Kp = Kh + (size_t)bh * SEQ * HDIM;
    const short* Vp = Vh + (size_t)bh * SEQ * HDIM;
    short* Op = O + (size_t)b * SEQ * D_DIM + h * HDIM;

    const int ksrc = (t & 7) ^ ((t >> 3) & 7);
    const int vr2 = (t & 31) * 2, vg = (t >> 5) * 8;
    const int swz = (q_own & 7) << 3;

    bf16x8 ones;
    #pragma unroll
    for (int j = 0; j < 8; ++j) ones[j] = (short)0x3F80;   // bf16 1.0

    const int npm = CAUSAL ? 2 : 1;
    for (int pm = 0; pm < npm; ++pm) {
        const int qt = CAUSAL ? (pm == 0 ? qsel : 15 - qsel) : qsel;
        const int q0 = qt * 128;
        const int qw = q0 + wave * 32;

        bf16x8 qf[4];
        #pragma unroll
        for (int s = 0; s < 4; ++s)
            qf[s] = *(const bf16x8*)(Qp + (size_t)(qw + q_own) * HDIM
                                     + s * 16 + hi * 8);

        int qkb[4], pvb[8], vwb[8], kgb;
        #pragma unroll
        for (int s = 0; s < 4; ++s)
            qkb[s] = q_own * 128 + 2 * ((s * 16 + hi * 8) ^ swz);
        #pragma unroll
        for (int ks = 0; ks < 8; ++ks)
            pvb[ks] = 32768 + q_own * 256 + 2 * ((ks * 16 + hi * 8) ^ swz);
        #pragma unroll
        for (int j = 0; j < 8; ++j)
            vwb[j] = 32768 + (vg + j) * 256 + 2 * (vr2 ^ (j << 3));
        kgb = t * 16;

        f32x16 oacc[2] = {};
        f32x16 lsum = {};
        float m_ = 0.0f;                 // safe: exp2 only after <=8 clamp
        const int nkt = CAUSAL ? (qt + 1) : (SEQ / 128);

        bf16x8 va0, vb0, va1, vb1;

        if (pm) __syncthreads();   // previous pass's LDS reads complete

        // ---- prologue: stage tile 0 ----
        #pragma unroll
        for (int c = 0; c < 4; ++c) {
            const int row = c * 32 + (t >> 3);
            GLOAD_LDS16(Kp + (size_t)row * HDIM + ksrc * 8,
                        ldsb + kgb + c * 4096);
        }
        va0 = *(const bf16x8*)(Vp + (size_t)vr2 * HDIM + vg);
        vb0 = *(const bf16x8*)(Vp + (size_t)(vr2 + 1) * HDIM + vg);
        va1 = *(const bf16x8*)(Vp + (size_t)(64 + vr2) * HDIM + vg);
        vb1 = *(const bf16x8*)(Vp + (size_t)(65 + vr2) * HDIM + vg);
        #pragma unroll
        for (int j = 0; j < 8; ++j) {
            unsigned int p0 = ((unsigned int)(unsigned short)vb0[j] << 16)
                            | (unsigned short)va0[j];
            unsigned int p1 = ((unsigned int)(unsigned short)vb1[j] << 16)
                            | (unsigned short)va1[j];
            *(unsigned int*)(ldsb + vwb[j])       = p0;
            *(unsigned int*)(ldsb + vwb[j] + 128) = p1;
        }
        __syncthreads();
        kgb ^= 16384;                          // K write side -> buf1
        if (!VSINGLE) {
            #pragma unroll
            for (int j = 0; j < 8; ++j) vwb[j] ^= 16384;
        }

        for (int kt = 0; kt < nkt; ++kt) {
            const int kbase = kt * 128;
            const bool have_next = (kt + 1 < nkt);

            if (have_next) {                    // fly under compute
                #pragma unroll
                for (int c = 0; c < 4; ++c) {
                    const int row = kbase + 128 + c * 32 + (t >> 3);
                    GLOAD_LDS16(Kp + (size_t)row * HDIM + ksrc * 8,
                                ldsb + kgb + c * 4096);
                }
                va0 = *(const bf16x8*)(Vp + (size_t)(kbase + 128 + vr2) * HDIM + vg);
                vb0 = *(const bf16x8*)(Vp + (size_t)(kbase + 129 + vr2) * HDIM + vg);
                va1 = *(const bf16x8*)(Vp + (size_t)(kbase + 192 + vr2) * HDIM + vg);
                vb1 = *(const bf16x8*)(Vp + (size_t)(kbase + 193 + vr2) * HDIM + vg);
            }

            // ---- QK^T with C = -m_ (pre-shifted scores)
            f32x16 minit;
            #pragma unroll
            for (int rr = 0; rr < 16; ++rr) minit[rr] = -m_;
            f32x16 sc[4];
            sc[0] = minit; sc[1] = minit; sc[2] = minit; sc[3] = minit;
            __builtin_amdgcn_s_setprio(1);
            #pragma unroll
            for (int kt2 = 0; kt2 < 4; ++kt2) {
                #pragma unroll
                for (int s = 0; s < 4; ++s) {
                    bf16x8 kf = *(const bf16x8*)(ldsb + qkb[s] + kt2 * 4096);
                    sc[kt2] = __builtin_amdgcn_mfma_f32_32x32x16_bf16(
                        kf, qf[s], sc[kt2], 0, 0, 0);
                }
            }
            __builtin_amdgcn_s_setprio(0);

            // ---- causal mask (k = kbase + kt2*32 + crow(rr,hi))
            if (CAUSAL && (kbase + 127 > qw)) {
                #pragma unroll
                for (int kt2 = 0; kt2 < 4; ++kt2)
                    #pragma unroll
                    for (int rr = 0; rr < 16; ++rr) {
                        const int k = kbase + kt2 * 32
                                    + (rr & 3) + 8 * (rr >> 2) + 4 * hi;
                        if (k > qw + q_own) sc[kt2][rr] = -1e30f;
                    }
            }

            // ---- shifted max (max3 tree); defer-max (T13)
            float km[4];
            #pragma unroll
            for (int kt2 = 0; kt2 < 4; ++kt2) {
                float t0 = fmaxf(fmaxf(sc[kt2][0],  sc[kt2][1]),  sc[kt2][2]);
                float t1 = fmaxf(fmaxf(sc[kt2][3],  sc[kt2][4]),  sc[kt2][5]);
                float t2 = fmaxf(fmaxf(sc[kt2][6],  sc[kt2][7]),  sc[kt2][8]);
                float t3 = fmaxf(fmaxf(sc[kt2][9],  sc[kt2][10]), sc[kt2][11]);
                float t4 = fmaxf(fmaxf(sc[kt2][12], sc[kt2][13]), sc[kt2][14]);
                float u  = fmaxf(fmaxf(t0, t1), t2);
                float v  = fmaxf(fmaxf(t3, t4), sc[kt2][15]);
                km[kt2] = fmaxf(u, v);
            }
            float smax = fmaxf(fmaxf(fmaxf(km[0], km[1]), km[2]), km[3]);
            smax = fmaxf(smax, __shfl_xor(smax, 32));   // shifted row max

            if (!__all(smax <= 8.0f)) {
                const float sp = fmaxf(smax, 0.f);
                const float corr = exp2f(-sp);
                lsum[0] *= corr;                // only element 0 is read
                #pragma unroll
                for (int ht = 0; ht < 2; ++ht)
                    #pragma unroll
                    for (int rr = 0; rr < 16; ++rr)
                        oacc[ht][rr] *= corr;
                #pragma unroll
                for (int kt2 = 0; kt2 < 4; ++kt2)
                    #pragma unroll
                    for (int rr = 0; rr < 16; ++rr)
                        sc[kt2][rr] -= sp;
                m_ += sp;
            }

            // ---- exp2 (args <= 8); sums come from the ones-MFMA below
            #pragma unroll
            for (int kt2 = 0; kt2 < 4; ++kt2)
                #pragma unroll
                for (int rr = 0; rr < 16; ++rr)
                    sc[kt2][rr] = exp2f(sc[kt2][rr]);

            // ---- pack P to bf16 B-fragments (cvt_pk + v_permlane32_swap)
            u32x4 paw[8];
            #pragma unroll
            for (int kt2 = 0; kt2 < 4; ++kt2) {
                unsigned int w0a = cvtpk(sc[kt2][0],  sc[kt2][1]);
                unsigned int w0b = cvtpk(sc[kt2][2],  sc[kt2][3]);
                unsigned int w1a = cvtpk(sc[kt2][4],  sc[kt2][5]);
                unsigned int w1b = cvtpk(sc[kt2][6],  sc[kt2][7]);
                unsigned int w2a = cvtpk(sc[kt2][8],  sc[kt2][9]);
                unsigned int w2b = cvtpk(sc[kt2][10], sc[kt2][11]);
                unsigned int w3a = cvtpk(sc[kt2][12], sc[kt2][13]);
                unsigned int w3b = cvtpk(sc[kt2][14], sc[kt2][15]);
                asm("v_permlane32_swap_b32 %0, %1" : "+v"(w0a), "+v"(w1a));
                asm("v_permlane32_swap_b32 %0, %1" : "+v"(w0b), "+v"(w1b));
                asm("v_permlane32_swap_b32 %0, %1" : "+v"(w2a), "+v"(w3a));
                asm("v_permlane32_swap_b32 %0, %1" : "+v"(w2b), "+v"(w3b));
                paw[kt2 * 2 + 0][0] = w0a; paw[kt2 * 2 + 0][1] = w0b;
                paw[kt2 * 2 + 0][2] = w1a; paw[kt2 * 2 + 0][3] = w1b;
                paw[kt2 * 2 + 1][0] = w2a; paw[kt2 * 2 + 1][1] = w2b;
                paw[kt2 * 2 + 1][2] = w3a; paw[kt2 * 2 + 1][3] = w3b;
            }

            // ---- PV: O^T[hd][q] += V^T[hd][k=128] . P^T[k][q]; l via ones
            __builtin_amdgcn_s_setprio(1);
            #pragma unroll
            for (int ks = 0; ks < 8; ++ks) {
                union { u32x4 u; bf16x8 bv8; } pc;
                pc.u = paw[ks];
                bf16x8 vf0 = *(const bf16x8*)(ldsb + pvb[ks]);
                oacc[0] = __builtin_amdgcn_mfma_f32_32x32x16_bf16(
                    vf0, pc.bv8, oacc[0], 0, 0, 0);
                bf16x8 vf1 = *(const bf16x8*)(ldsb + pvb[ks] + 8192);
                oacc[1] = __builtin_amdgcn_mfma_f32_32x32x16_bf16(
                    vf1, pc.bv8, oacc[1], 0, 0, 0);
                lsum = __builtin_amdgcn_mfma_f32_32x32x16_bf16(
                    ones, pc.bv8, lsum, 0, 0, 0);
            }
            __builtin_amdgcn_s_setprio(0);

            if (have_next) {
                if (VSINGLE) {
                    __syncthreads();   // all PV reads done; drains gll + vmem
                    #pragma unroll
                    for (int j = 0; j < 8; ++j) {
                        unsigned int p0 = ((unsigned int)(unsigned short)vb0[j] << 16)
                                        | (unsigned short)va0[j];
                        unsigned int p1 = ((unsigned int)(unsigned short)vb1[j] << 16)
                                        | (unsigned short)va1[j];
                        *(unsigned int*)(ldsb + vwb[j])       = p0;
                        *(unsigned int*)(ldsb + vwb[j] + 128) = p1;
                    }
                    __syncthreads();   // V visible; K buf[nxt] ready
                } else {
                    #pragma unroll
                    for (int j = 0; j < 8; ++j) {
                        unsigned int p0 = ((unsigned int)(unsigned short)vb0[j] << 16)
                                        | (unsigned short)va0[j];
                        unsigned int p1 = ((unsigned int)(unsigned short)vb1[j] << 16)
                                        | (unsigned short)va1[j];
                        *(unsigned int*)(ldsb + vwb[j])       = p0;
                        *(unsigned int*)(ldsb + vwb[j] + 128) = p1;
                    }
                    __syncthreads();
                }
            }
            // flip K buffers (V only when double-buffered)
            kgb ^= 16384;
            #pragma unroll
            for (int s = 0; s < 4; ++s) qkb[s] ^= 16384;
            if (!VSINGLE) {
                #pragma unroll
                for (int ks = 0; ks < 8; ++ks) pvb[ks] ^= 16384;
                #pragma unroll
                for (int j = 0; j < 8; ++j) vwb[j] ^= 16384;
            }
        }

        // ---- epilogue: O[q = qw+q_own][hd = ht*32 + 8j + 4hi + 0..3]
        const float inv = 1.0f / lsum[0];
        const int grow = qw + q_own;
        #pragma unroll
        for (int ht = 0; ht < 2; ++ht)
            #pragma unroll
            for (int j = 0; j < 4; ++j) {
                ushort4 o;
                o.x = (unsigned short)f2bf(oacc[ht][4 * j + 0] * inv);
                o.y = (unsigned short)f2bf(oacc[ht][4 * j + 1] * inv);
                o.z = (unsigned short)f2bf(oacc[ht][4 * j + 2] * inv);
                o.w = (unsigned short)f2bf(oacc[ht][4 * j + 3] * inv);
                *(ushort4*)&Op[(size_t)grow * D_DIM + ht * 32 + 8 * j + 4 * hi] = o;
            }
    }
}

// Standalone attention (non-causal path): 64KB double-buffer (grid 2/CU).
template<bool CAUSAL>
__global__ __launch_bounds__(256, 2) void attn_mfma_kernel(
    const short* __restrict__ Qh, const short* __restrict__ Kh,
    const short* __restrict__ Vh, short* __restrict__ O)
{
    __shared__ short lds[32768];
    attn_body<CAUSAL, false>((char*)lds, Qh, Kh, Vh, O, blockIdx.x);
}

// Fused: blocks 0..255 = causal attention (V single-buffered, 48KB -> HW can
// co-reside 3 blocks/CU; launch_bounds stays (256,2) so VGPR isn't capped);
// blocks 256..767 = K2/V2 projection GEMM.
__global__ __launch_bounds__(256, 2) void fused_cattn_kv2_kernel(
    const short* __restrict__ Qh, const short* __restrict__ Kh,
    const short* __restrict__ Vh, short* __restrict__ O,
    const short* __restrict__ A2, const short* __restrict__ Bt2,
    const float* __restrict__ bias2,
    short* __restrict__ Kh2, short* __restrict__ Vh2)
{
    __shared__ short lds[24576];   // 48KB
    if (blockIdx.x < 256) {
        attn_body<true, true>((char*)lds, Qh, Kh, Vh, O, blockIdx.x);
    } else {
        const int bx2 = blockIdx.x - 256;        // 512 blocks: (32 m) x (16 n)
        gemm_qkv_body(lds, lds + 4096, A2, Bt2, bias2,
                      nullptr, Kh2, Vh2, 1024, 1.0f, bx2 & 31, bx2 >> 5);
    }
}

// ---------------------------------------------------------------------------
// LayerNorm rows of 1024; optional bf16 side output. In-place safe.
// ---------------------------------------------------------------------------
__global__ __launch_bounds__(256) void ln_kernel(
    const float* __restrict__ X, const float* __restrict__ g,
    const float* __restrict__ bb, float* __restrict__ outf,
    short* __restrict__ outb)
{
    const int row = blockIdx.x;
    const int t = threadIdx.x;
    const float* x = X + (size_t)row * D_DIM;
    float4 v = *(const float4*)(x + (t << 2));
    float s  = v.x + v.y + v.z + v.w;
    float sq = v.x * v.x + v.y * v.y + v.z * v.z + v.w * v.w;
    #pragma unroll
    for (int off = 1; off < 64; off <<= 1) {
        s  += __shfl_xor(s, off);
        sq += __shfl_xor(sq, off);
    }
    __shared__ float ss[4], ssq[4];
    const int wid = t >> 6, lane = t & 63;
    if (lane == 0) { ss[wid] = s; ssq[wid] = sq; }
    __syncthreads();
    s  = ss[0] + ss[1] + ss[2] + ss[3];
    sq = ssq[0] + ssq[1] + ssq[2] + ssq[3];
    const float mean = s * (1.0f / 1024.0f);
    const float var  = sq * (1.0f / 1024.0f) - mean * mean;
    const float inv  = rsqrtf(var + 1e-5f);
    float4 gv = *(const float4*)(g  + (t << 2));
    float4 bv = *(const float4*)(bb + (t << 2));
    float4 o;
    o.x = gv.x * (v.x - mean) * inv + bv.x;
    o.y = gv.y * (v.y - mean) * inv + bv.y;
    o.z = gv.z * (v.z - mean) * inv + bv.z;
    o.w = gv.w * (v.w - mean) * inv + bv.w;
    if (outf) *(float4*)(outf + (size_t)row * D_DIM + (t << 2)) = o;
    if (outb) {
        ushort4 ob;
        ob.x = (unsigned short)f2bf(o.x); ob.y = (unsigned short)f2bf(o.y);
        ob.z = (unsigned short)f2bf(o.z); ob.w = (unsigned short)f2bf(o.w);
        *(ushort4*)(outb + (size_t)row * D_DIM + (t << 2)) = ob;
    }
}

// ---------------------------------------------------------------------------
extern "C" void kernel_launch(void* const* d_in, const int* in_sizes, int n_in,
                              void* d_out, int out_size, void* d_ws, size_t ws_size,
                              hipStream_t stream)
{
    (void)in_sizes; (void)n_in; (void)out_size; (void)ws_size;
    const float* S0f = (const float*)d_in[0];
    const float* Hf  = (const float*)d_in[1];
    const float* bq1 = (const float*)d_in[3];
    const float* bk1 = (const float*)d_in[5];
    const float* bv1 = (const float*)d_in[7];
    const float* bo1 = (const float*)d_in[9];
    const float* g1  = (const float*)d_in[10]; const float* b1 = (const float*)d_in[11];
    const float* bq2 = (const float*)d_in[13];
    const float* bk2 = (const float*)d_in[15];
    const float* bv2 = (const float*)d_in[17];
    const float* bo2 = (const float*)d_in[19];
    const float* g2  = (const float*)d_in[20]; const float* b2 = (const float*)d_in[21];
    const float* bff = (const float*)d_in[23];
    const float* g3  = (const float*)d_in[24]; const float* b3 = (const float*)d_in[25];

    char* ws = (char*)d_ws;
    size_t off = 0;
    auto alloc = [&](size_t bytes) { char* p = ws + off; off += (bytes + 255) & ~(size_t)255; return p; };
    short* Wt   = (short*)alloc((size_t)9 * D_DIM * D_DIM * 2);   // 18 MB
    short* bS0  = (short*)alloc((size_t)MROWS * D_DIM * 2);       // 8 MB
    short* bH   = (short*)alloc((size_t)MROWS * D_DIM * 2);       // 8 MB
    short* Qhb  = (short*)alloc((size_t)MROWS * D_DIM * 2);       // 8 MB head-major
    short* Khb  = (short*)alloc((size_t)MROWS * D_DIM * 2);       // 8 MB
    short* Vhb  = (short*)alloc((size_t)MROWS * D_DIM * 2);       // 8 MB
    short* Khb2 = (short*)alloc((size_t)MROWS * D_DIM * 2);       // 8 MB (L2 K)
    short* Vhb2 = (short*)alloc((size_t)MROWS * D_DIM * 2);       // 8 MB (L2 V)
    short* bAO  = (short*)alloc((size_t)MROWS * D_DIM * 2);       // 8 MB
    float* X    = (float*)alloc((size_t)MROWS * D_DIM * 4);       // 16 MB
    short* bSx  = (short*)alloc((size_t)MROWS * D_DIM * 2);       // 8 MB
    float* cb1  = (float*)alloc(3072 * 4);
    float* cb2  = (float*)alloc(2048 * 4);

    const size_t WSTRIDE = (size_t)D_DIM * D_DIM;
    const float QSCALE = 0.125f * 1.44269504088896f;   // 1/sqrt(64) * log2(e)

    WPtrs wp;
    wp.p[0] = (const float*)d_in[2];   // Wq1
    wp.p[1] = (const float*)d_in[4];   // Wk1
    wp.p[2] = (const float*)d_in[6];   // Wv1
    wp.p[3] = (const float*)d_in[8];   // Wo1
    wp.p[4] = (const float*)d_in[12];  // Wq2
    wp.p[5] = (const float*)d_in[14];  // Wk2
    wp.p[6] = (const float*)d_in[16];  // Wv2
    wp.p[7] = (const float*)d_in[18];  // Wo2
    wp.p[8] = (const float*)d_in[22];  // Wf

    prep_kernel<<<dim3(6420), 256, 0, stream>>>(
        wp, Wt, S0f, Hf, bS0, bH, bq1, bk1, bv1, bk2, bv2, cb1, cb2);

    const dim3 blk(256);
    const dim3 attn_grid_f(512);             // full: 16 q-tiles x 32 bh
    const dim3 resid_grid(32, 16);           // 128x64 tiles, 512 blocks

    // ---- layer 1: causal self-attention (fused with K2/V2 projection) ----
    gemm_qkv_kernel<<<dim3(32, 24), blk, 0, stream>>>(
        bS0, Wt, cb1, Qhb, Khb, Vhb, 0, QSCALE);
    fused_cattn_kv2_kernel<<<dim3(768), blk, 0, stream>>>(
        Qhb, Khb, Vhb, bAO, bH, Wt + 5 * WSTRIDE, cb2, Khb2, Vhb2);
    gemm_resid_kernel<<<resid_grid, blk, 0, stream>>>(
        bAO, Wt + 3 * WSTRIDE, bo1, S0f, X);
    ln_kernel<<<MROWS, blk, 0, stream>>>(X, g1, b1, X, bSx);

    // ---- layer 2: cross-attention over H ----
    gemm_q_kernel<<<resid_grid, blk, 0, stream>>>(
        bSx, Wt + 4 * WSTRIDE, bq2, Qhb, QSCALE);
    attn_mfma_kernel<false><<<attn_grid_f, blk, 0, stream>>>(
        Qhb, Khb2, Vhb2, bAO);
    gemm_resid_kernel<<<resid_grid, blk, 0, stream>>>(
        bAO, Wt + 7 * WSTRIDE, bo2, X, X);
    ln_kernel<<<MROWS, blk, 0, stream>>>(X, g2, b2, X, bSx);

    // ---- FFN ----
    gemm_resid_kernel<<<resid_grid, blk, 0, stream>>>(
        bSx, Wt + 8 * WSTRIDE, bff, X, X);
    ln_kernel<<<MROWS, blk, 0, stream>>>(X, g3, b3, (float*)d_out, nullptr);
}